// Round 4
// baseline (616.993 us; speedup 1.0000x reference)
//
#include <hip/hip_runtime.h>

static constexpr int N_NODES = 100000;
static constexpr int N_EDGES = 3200000;
static constexpr int IN_CH = 512;
static constexpr int H = 16;
static constexpr int TB = 256;

static constexpr int BN = 256;                       // nodes per bucket
static constexpr int NB = (N_NODES + BN - 1) / BN;   // 391 buckets
static constexpr int CAP = 8960;                     // ebuf slots/bucket (mean 8192, +8.5 sigma)
static constexpr int CAP2 = CAP + 3 * BN;            // 9728: sorted+padded slots (mult of 4)
static constexpr int CHUNK = 8192;                   // edges per scatter WG
static constexpr int GRID_SC = (N_EDGES + CHUNK - 1) / CHUNK;  // 391
static constexpr int NBLK64 = (N_NODES + 63) / 64;   // 1563
static constexpr int NBLK128 = (N_NODES + 127) / 128;  // 782 (8-ch gather grid)

typedef int vi4 __attribute__((ext_vector_type(4)));
typedef float vf4 __attribute__((ext_vector_type(4)));

// gcur[b] = b*CAP  (bump cursors into fixed-capacity bucket regions)
__global__ void k_init(int* __restrict__ gcur) {
  int b = blockIdx.x * blockDim.x + threadIdx.x;
  if (b < NB) gcur[b] = b * CAP;
}

// Chunked reserve-then-write scatter (one contiguous run per (WG,bucket)).
// pack = (dst&255)<<17 | src  (src < 2^17)
__global__ void k_cscatter(const int* __restrict__ ei, int* __restrict__ gcur,
                           int* __restrict__ ebuf) {
  __shared__ int cnt[NB];
  __shared__ int gofs[NB];
  int t = threadIdx.x;
  int c0 = blockIdx.x * CHUNK;
  int c1 = min(c0 + CHUNK, N_EDGES);
  for (int b = t; b < NB; b += TB) cnt[b] = 0;
  __syncthreads();
  for (int j = c0 + t; j < c1; j += TB) atomicAdd(&cnt[ei[N_EDGES + j] >> 8], 1);
  __syncthreads();
  for (int b = t; b < NB; b += TB)
    if (cnt[b] > 0) gofs[b] = atomicAdd(&gcur[b], cnt[b]);
  __syncthreads();
  for (int j = c0 + t; j < c1; j += TB) {
    int s = ei[j];
    int d = ei[N_EDGES + j];
    int slot = atomicAdd(&gofs[d >> 8], 1);
    ebuf[slot] = ((d & 255) << 17) | s;
  }
}

// Per-bucket counting sort with 4-slot-aligned per-node runs; pads point at
// dummy node N_NODES (table row N = zeros). Emits nrs/nend and disq.
__global__ void k_bsort(const int* __restrict__ gcur, const int* __restrict__ ebuf,
                        int* __restrict__ ebuf2, int* __restrict__ nrs,
                        int* __restrict__ nend, float* __restrict__ disq) {
  __shared__ int cnt[BN];
  __shared__ int pre[BN];
  __shared__ int cur[BN];
  int b = blockIdx.x, t = threadIdx.x;
  cnt[t] = 0;
  __syncthreads();
  int beg = b * CAP, end = gcur[b];
  for (int j = beg + t; j < end; j += TB) atomicAdd(&cnt[ebuf[j] >> 17], 1);
  __syncthreads();
  int myc = cnt[t];
  int ac = (myc + 3) & ~3;
  pre[t] = ac;
  __syncthreads();
  for (int off = 1; off < TB; off <<= 1) {
    int v = (t >= off) ? pre[t - off] : 0;
    __syncthreads();
    pre[t] += v;
    __syncthreads();
  }
  int start = b * CAP2 + ((t == 0) ? 0 : pre[t - 1]);
  cur[t] = start;
  int node = b * BN + t;
  if (node < N_NODES) {
    nrs[node] = start;
    nend[node] = start + ac;
    disq[node] = 1.0f / sqrtf((float)myc + 1.0f);
    for (int j = start + myc; j < start + ac; j++) ebuf2[j] = N_NODES;  // dummy pads
  }
  __syncthreads();
  for (int j = beg + t; j < end; j += TB) {
    int p = ebuf[j];
    int slot = atomicAdd(&cur[p >> 17], 1);
    ebuf2[slot] = p & 0x1FFFF;
  }
}

// tlo[r][0..7] = (X@W1)[r][0..7]*disq[r]; thi = channels 8..15. Row N = zeros.
__global__ void k_gemm1(const float* __restrict__ x, const float* __restrict__ W,
                        const float* __restrict__ disq,
                        float* __restrict__ tlo, float* __restrict__ thi) {
  int r = blockIdx.x * blockDim.x + threadIdx.x;
  if (r > N_NODES) return;
  float4* olo = (float4*)(tlo + (size_t)r * 8);
  float4* ohi = (float4*)(thi + (size_t)r * 8);
  if (r == N_NODES) {  // dummy row for gather pads
    float4 z = make_float4(0.f, 0.f, 0.f, 0.f);
    olo[0] = z; olo[1] = z; ohi[0] = z; ohi[1] = z;
    return;
  }
  const float4* xr = (const float4*)(x + (size_t)r * IN_CH);
  float acc[H];
#pragma unroll
  for (int c = 0; c < H; c++) acc[c] = 0.f;
  for (int k4 = 0; k4 < IN_CH / 4; k4++) {
    float4 xv = xr[k4];
    const float* wr = W + k4 * 4 * H;
    float xs[4] = {xv.x, xv.y, xv.z, xv.w};
#pragma unroll
    for (int j = 0; j < 4; j++) {
#pragma unroll
      for (int c = 0; c < H; c++) acc[c] = fmaf(xs[j], wr[j * H + c], acc[c]);
    }
  }
  float dn = disq[r];
  olo[0] = make_float4(acc[0] * dn, acc[1] * dn, acc[2] * dn, acc[3] * dn);
  olo[1] = make_float4(acc[4] * dn, acc[5] * dn, acc[6] * dn, acc[7] * dn);
  ohi[0] = make_float4(acc[8] * dn, acc[9] * dn, acc[10] * dn, acc[11] * dn);
  ohi[1] = make_float4(acc[12] * dn, acc[13] * dn, acc[14] * dn, acc[15] * dn);
}

// 8-channel gather pass over a 3.2MB half-table (L2-resident by design).
// 2 lanes/node, float4 per lane. ebuf2 via NT loads, agg via NT stores so the
// table keeps L2. agg[node][0..7] = (sum_nbrs tbl[src] + tbl[node]) * disq[node].
__global__ void k_gath8(const int* __restrict__ nrs, const int* __restrict__ nend,
                        const int* __restrict__ ebuf2, const float* __restrict__ disq,
                        const float* __restrict__ tbl, float* __restrict__ agg) {
  int b = blockIdx.x, t = threadIdx.x;
  int nl = t >> 1, q = t & 1;
  int node = b * 128 + nl;
  if (node >= N_NODES) return;
  const float4* t4 = (const float4*)tbl;
  int beg = nrs[node], endp = nend[node];
  float4 acc = make_float4(0.f, 0.f, 0.f, 0.f);
  for (int j = beg; j < endp; j += 4) {
    vi4 s = __builtin_nontemporal_load((const vi4*)(ebuf2 + j));
    float4 a0 = t4[s.x * 2 + q];
    float4 a1 = t4[s.y * 2 + q];
    float4 a2 = t4[s.z * 2 + q];
    float4 a3 = t4[s.w * 2 + q];
    acc.x += (a0.x + a1.x) + (a2.x + a3.x);
    acc.y += (a0.y + a1.y) + (a2.y + a3.y);
    acc.z += (a0.z + a1.z) + (a2.z + a3.z);
    acc.w += (a0.w + a1.w) + (a2.w + a3.w);
  }
  float4 sf = t4[node * 2 + q];
  float dn = disq[node];
  vf4 r;
  r.x = (acc.x + sf.x) * dn;
  r.y = (acc.y + sf.y) * dn;
  r.z = (acc.z + sf.z) * dn;
  r.w = (acc.w + sf.w) * dn;
  __builtin_nontemporal_store(r, (vf4*)(agg + (size_t)node * 8 + q * 4));
}

// Inter-layer dense: v = relu(agg + bias); out = (v @ W2) * disq, split lo/hi.
// Row N = zeros (pads for next gather).
__global__ void k_mid(const float* __restrict__ aggLo, const float* __restrict__ aggHi,
                      const float* __restrict__ W2, const float* __restrict__ bias,
                      const float* __restrict__ disq,
                      float* __restrict__ tlo, float* __restrict__ thi) {
  __shared__ float w[256];
  int t = threadIdx.x;
  w[t] = W2[t];
  __syncthreads();
  int r = blockIdx.x * 256 + t;
  if (r > N_NODES) return;
  float4* olo = (float4*)(tlo + (size_t)r * 8);
  float4* ohi = (float4*)(thi + (size_t)r * 8);
  if (r == N_NODES) {
    float4 z = make_float4(0.f, 0.f, 0.f, 0.f);
    olo[0] = z; olo[1] = z; ohi[0] = z; ohi[1] = z;
    return;
  }
  float v[16];
  float4 a;
  a = *(const float4*)(aggLo + (size_t)r * 8);
  v[0] = a.x; v[1] = a.y; v[2] = a.z; v[3] = a.w;
  a = *(const float4*)(aggLo + (size_t)r * 8 + 4);
  v[4] = a.x; v[5] = a.y; v[6] = a.z; v[7] = a.w;
  a = *(const float4*)(aggHi + (size_t)r * 8);
  v[8] = a.x; v[9] = a.y; v[10] = a.z; v[11] = a.w;
  a = *(const float4*)(aggHi + (size_t)r * 8 + 4);
  v[12] = a.x; v[13] = a.y; v[14] = a.z; v[15] = a.w;
#pragma unroll
  for (int i = 0; i < 16; i++) v[i] = fmaxf(v[i] + bias[i], 0.f);
  float4 o[4];
#pragma unroll
  for (int c4 = 0; c4 < 4; c4++) o[c4] = make_float4(0.f, 0.f, 0.f, 0.f);
#pragma unroll
  for (int i = 0; i < 16; i++) {
    float vi = v[i];
#pragma unroll
    for (int c4 = 0; c4 < 4; c4++) {
      float4 wv = *(const float4*)(w + i * 16 + c4 * 4);
      o[c4].x = fmaf(vi, wv.x, o[c4].x);
      o[c4].y = fmaf(vi, wv.y, o[c4].y);
      o[c4].z = fmaf(vi, wv.z, o[c4].z);
      o[c4].w = fmaf(vi, wv.w, o[c4].w);
    }
  }
  float dn = disq[r];
#pragma unroll
  for (int c4 = 0; c4 < 4; c4++) {
    o[c4].x *= dn; o[c4].y *= dn; o[c4].z *= dn; o[c4].w *= dn;
  }
  olo[0] = o[0]; olo[1] = o[1]; ohi[0] = o[2]; ohi[1] = o[3];
}

// Final dense: hs3 = relu(agg + b2) . W3 * disq. Row N = 0.
__global__ void k_last(const float* __restrict__ aggLo, const float* __restrict__ aggHi,
                       const float* __restrict__ W3, const float* __restrict__ bias,
                       const float* __restrict__ disq, float* __restrict__ hs3) {
  __shared__ float w3[16];
  int t = threadIdx.x;
  if (t < 16) w3[t] = W3[t];
  __syncthreads();
  int r = blockIdx.x * 256 + t;
  if (r > N_NODES) return;
  if (r == N_NODES) { hs3[r] = 0.f; return; }
  float v[16];
  float4 a;
  a = *(const float4*)(aggLo + (size_t)r * 8);
  v[0] = a.x; v[1] = a.y; v[2] = a.z; v[3] = a.w;
  a = *(const float4*)(aggLo + (size_t)r * 8 + 4);
  v[4] = a.x; v[5] = a.y; v[6] = a.z; v[7] = a.w;
  a = *(const float4*)(aggHi + (size_t)r * 8);
  v[8] = a.x; v[9] = a.y; v[10] = a.z; v[11] = a.w;
  a = *(const float4*)(aggHi + (size_t)r * 8 + 4);
  v[12] = a.x; v[13] = a.y; v[14] = a.z; v[15] = a.w;
  float o = 0.f;
#pragma unroll
  for (int i = 0; i < 16; i++) o = fmaf(fmaxf(v[i] + bias[i], 0.f), w3[i], o);
  hs3[r] = o * disq[r];
}

// Final 1-channel gather: 4 lanes/node, int4 index loads, shfl reduce.
__global__ void k_gath1(const int* __restrict__ nrs, const int* __restrict__ nend,
                        const int* __restrict__ ebuf2, const float* __restrict__ disq,
                        const float* __restrict__ hs3, const float* __restrict__ bias,
                        float* __restrict__ out) {
  int b = blockIdx.x, t = threadIdx.x;
  int nl = t >> 2, lane = t & 3;
  int node = b * 64 + nl;
  if (node >= N_NODES) return;
  int beg = nrs[node], endp = nend[node];
  float acc = 0.f;
  for (int j = beg + 4 * lane; j < endp; j += 16) {
    vi4 s = __builtin_nontemporal_load((const vi4*)(ebuf2 + j));
    acc += (hs3[s.x] + hs3[s.y]) + (hs3[s.z] + hs3[s.w]);
  }
  acc += __shfl_xor(acc, 1);
  acc += __shfl_xor(acc, 2);
  if (lane == 0) out[node] = fmaf(acc + hs3[node], disq[node], bias[0]);
}

extern "C" void kernel_launch(void* const* d_in, const int* in_sizes, int n_in,
                              void* d_out, int out_size, void* d_ws, size_t ws_size,
                              hipStream_t stream) {
  const float* x = (const float*)d_in[0];
  const int* ei = (const int*)d_in[1];  // integer inputs delivered as int32
  const float* W1 = (const float*)d_in[2];
  const float* b1 = (const float*)d_in[3];
  const float* W2 = (const float*)d_in[4];
  const float* b2 = (const float*)d_in[5];
  const float* W3 = (const float*)d_in[6];
  const float* b3 = (const float*)d_in[7];
  float* out = (float*)d_out;

  // Workspace (~55 MB), 16B-aligned segments.
  int* ebuf = (int*)d_ws;                        // NB*CAP (14.0 MB)
  int* ebuf2 = ebuf + (size_t)NB * CAP;          // NB*CAP2 (15.2 MB), %4==0 offset
  int* gcur = ebuf2 + (size_t)NB * CAP2;         // NB
  int* nrs = gcur + NB;                          // N
  int* nend = nrs + N_NODES;                     // N
  int pad = (4 - ((NB + 2 * N_NODES) & 3)) & 3;  // realign to 16B
  float* disq = (float*)(nend + N_NODES + pad);  // N
  float* tloA = disq + N_NODES;                  // 8*(N+1) each: layer-1 half-tables
  float* thiA = tloA + (size_t)(N_NODES + 1) * 8;
  float* tloB = thiA + (size_t)(N_NODES + 1) * 8;  // layer-2 half-tables
  float* thiB = tloB + (size_t)(N_NODES + 1) * 8;
  float* aggLo = thiB + (size_t)(N_NODES + 1) * 8;  // 8*N partial aggregates (reused)
  float* aggHi = aggLo + (size_t)N_NODES * 8;
  float* hs3 = aggHi + (size_t)N_NODES * 8;      // N+1

  k_init<<<(NB + 63) / 64, 64, 0, stream>>>(gcur);
  k_cscatter<<<GRID_SC, TB, 0, stream>>>(ei, gcur, ebuf);
  k_bsort<<<NB, TB, 0, stream>>>(gcur, ebuf, ebuf2, nrs, nend, disq);

  // Layer 1 dense part (+ dummy rows)
  k_gemm1<<<(N_NODES + 64) / 64, 64, 0, stream>>>(x, W1, disq, tloA, thiA);
  // Layer 1 aggregation: two sequential 8-ch passes (each table half L2-fits)
  k_gath8<<<NBLK128, TB, 0, stream>>>(nrs, nend, ebuf2, disq, tloA, aggLo);
  k_gath8<<<NBLK128, TB, 0, stream>>>(nrs, nend, ebuf2, disq, thiA, aggHi);
  // Layer 2 dense 16x16
  k_mid<<<(N_NODES + 256) / 256, 256, 0, stream>>>(aggLo, aggHi, W2, b1, disq, tloB, thiB);
  // Layer 2 aggregation: two sequential 8-ch passes
  k_gath8<<<NBLK128, TB, 0, stream>>>(nrs, nend, ebuf2, disq, tloB, aggLo);
  k_gath8<<<NBLK128, TB, 0, stream>>>(nrs, nend, ebuf2, disq, thiB, aggHi);
  // Layer 3 dense 16x1
  k_last<<<(N_NODES + 256) / 256, 256, 0, stream>>>(aggLo, aggHi, W3, b2, disq, hs3);
  // Layer 3 aggregation
  k_gath1<<<NBLK64, TB, 0, stream>>>(nrs, nend, ebuf2, disq, hs3, b3, out);
}